// Round 6
// baseline (1261.191 us; speedup 1.0000x reference)
//
#include <hip/hip_runtime.h>
#include <hip/hip_fp16.h>
#include <stdint.h>
#include <math.h>

#define HWS 16384
#define NPIX (16 * HWS)
#define T 128

// float offsets into d_ws. All weight matrices stored TRANSPOSED: [cin][out],
// so c-outer/o-inner accumulation reads contiguous runs of `out` floats.
enum {
  OFF_W1  = 0,      // [48][24] rb conv1 (bn-folded)
  OFF_B1  = 1152,   // 24
  OFF_W2  = 1176,   // [24][48] rb conv2 (post-residual bn folded)
  OFF_B2  = 2328,   // 48
  OFF_XS  = 2376,   // 48  bn scale applied to xs in residual add
  OFF_WQ  = 2424,   // [48][48]
  OFF_BQ  = 4728,   // 48
  OFF_WV  = 4776,   // [48][48]
  OFF_BV  = 7080,   // 48
  OFF_WK1 = 7128,   // [48][24]
  OFF_BK1 = 8280,   // 24
  OFF_WK2 = 8304,   // [48][24]
  OFF_BK2 = 9456,   // 24
  OFF_WCF = 9480,   // [96][48]
  OFF_BCF = 14088,  // 48
  OFF_WE1 = 14136,  // [48][24] emb conv1 (no bn)
  OFF_BE1 = 15288,  // 24
  OFF_WE2 = 15312,  // [24][48]
  OFF_BE2 = 16464,  // 48
  WS_TOTAL = 16512
};

struct PtrPack { const float* p[48]; };

// bn fold: s = g/sqrt(v+eps), t = beta - m*s;  bn(conv(x,W,b)) = (s.W)x + (s.b + t)
#define SCALE_T(bnb, o, s, t)                                       \
  {                                                                 \
    float g_ = P.p[(bnb)][(o)], be_ = P.p[(bnb) + 1][(o)];          \
    float m_ = P.p[(bnb) + 2][(o)], v_ = P.p[(bnb) + 3][(o)];       \
    s = g_ / sqrtf(v_ + 1e-5f);                                     \
    t = be_ - m_ * s;                                               \
  }

__global__ void fold_kernel(PtrPack P, float* __restrict__ W) {
  int i = blockIdx.x * blockDim.x + threadIdx.x;
  float s, t;
  if (i < OFF_B1)        { int j = i;            int ci = j / 24, o = j % 24; SCALE_T(4,  o, s, t); W[i] = s * P.p[2][o * 48 + ci]; }
  else if (i < OFF_W2)   { int o = i - OFF_B1;                                SCALE_T(4,  o, s, t); W[i] = s * P.p[3][o] + t; }
  else if (i < OFF_B2)   { int j = i - OFF_W2;   int ci = j / 48, o = j % 48; SCALE_T(10, o, s, t); W[i] = s * P.p[8][o * 24 + ci]; }
  else if (i < OFF_XS)   { int o = i - OFF_B2;                                SCALE_T(10, o, s, t); W[i] = s * P.p[9][o] + t; }
  else if (i < OFF_WQ)   { int o = i - OFF_XS;                                SCALE_T(10, o, s, t); W[i] = s; }
  else if (i < OFF_BQ)   { int j = i - OFF_WQ;   int ci = j / 48, o = j % 48; SCALE_T(16, o, s, t); W[i] = s * P.p[14][o * 48 + ci]; }
  else if (i < OFF_WV)   { int o = i - OFF_BQ;                                SCALE_T(16, o, s, t); W[i] = s * P.p[15][o] + t; }
  else if (i < OFF_BV)   { int j = i - OFF_WV;   int ci = j / 48, o = j % 48; SCALE_T(22, o, s, t); W[i] = s * P.p[20][o * 48 + ci]; }
  else if (i < OFF_WK1)  { int o = i - OFF_BV;                                SCALE_T(22, o, s, t); W[i] = s * P.p[21][o] + t; }
  else if (i < OFF_BK1)  { int j = i - OFF_WK1;  int ci = j / 24, o = j % 24; SCALE_T(28, o, s, t); W[i] = s * P.p[26][o * 48 + ci]; }
  else if (i < OFF_WK2)  { int o = i - OFF_BK1;                               SCALE_T(28, o, s, t); W[i] = s * P.p[27][o] + t; }
  else if (i < OFF_BK2)  { int j = i - OFF_WK2;  int ci = j / 24, o = j % 24; SCALE_T(34, o, s, t); W[i] = s * P.p[32][o * 48 + ci]; }
  else if (i < OFF_WCF)  { int o = i - OFF_BK2;                               SCALE_T(34, o, s, t); W[i] = s * P.p[33][o] + t; }
  else if (i < OFF_BCF)  { int j = i - OFF_WCF;  int ci = j / 48, o = j % 48; SCALE_T(40, o, s, t); W[i] = s * P.p[38][o * 96 + ci]; }
  else if (i < OFF_WE1)  { int o = i - OFF_BCF;                               SCALE_T(40, o, s, t); W[i] = s * P.p[39][o] + t; }
  else if (i < OFF_BE1)  { int j = i - OFF_WE1;  int ci = j / 24, o = j % 24; W[i] = P.p[44][o * 48 + ci]; }
  else if (i < OFF_WE2)  { int o = i - OFF_BE1;  W[i] = P.p[45][o]; }
  else if (i < OFF_BE2)  { int j = i - OFF_WE2;  int ci = j / 48, o = j % 48; W[i] = P.p[46][o * 24 + ci]; }
  else if (i < WS_TOTAL) { int o = i - OFF_BE2;  W[i] = P.p[47][o]; }
}

// ---------------- fused per-pixel forward, X-state in LDS as fp16 pairs ----------------

__device__ __forceinline__ float gelu_f(float x) {
  return 0.5f * x * (1.f + erff(x * 0.70710678118654752440f));
}

__global__ __attribute__((amdgpu_flat_work_group_size(T, T), amdgpu_waves_per_eu(3, 3)))
void fused_main(const float* __restrict__ x0g,
                const float* __restrict__ x1g,
                const float* __restrict__ W,
                float* __restrict__ out) {
  // Per-thread private column of channel-pairs; [cp][tid] layout ->
  // lane-consecutive addresses, conflict-free, no cross-thread sharing.
  __shared__ __half2 Xh[2][24][T];
  const int tid = threadIdx.x;
  const int p = blockIdx.x * T + tid;
  const int b = p >> 14;  // hw = 16384
  const int n = p & (HWS - 1);

  {
    const float* px0 = x0g + (size_t)b * 48 * HWS + n;
    const float* px1 = x1g + (size_t)b * 48 * HWS + n;
#pragma unroll 4
    for (int cp = 0; cp < 24; cp++) {
      Xh[0][cp][tid] = __floats2half2_rn(px0[(size_t)(2 * cp) * HWS], px0[(size_t)(2 * cp + 1) * HWS]);
      Xh[1][cp][tid] = __floats2half2_rn(px1[(size_t)(2 * cp) * HWS], px1[(size_t)(2 * cp + 1) * HWS]);
    }
  }

  float la[48];

#pragma unroll 1
  for (int k = 0; k < 4; k++) {
    // ---- residual blocks (in-place on Xh), c-outer accumulation ----
#pragma unroll 1
    for (int s = 0; s < 2; s++) {
      float r[24];
#pragma unroll
      for (int o = 0; o < 24; o++) r[o] = W[OFF_B1 + o];
#pragma unroll 2
      for (int cp = 0; cp < 24; cp++) {
        __half2 u = Xh[s][cp][tid];
        float x0c = __low2float(u), x1c = __high2float(u);
#pragma unroll
        for (int o = 0; o < 24; o++) {
          r[o] = fmaf(W[OFF_W1 + (2 * cp) * 24 + o], x0c, r[o]);
          r[o] = fmaf(W[OFF_W1 + (2 * cp + 1) * 24 + o], x1c, r[o]);
        }
      }
#pragma unroll
      for (int o = 0; o < 24; o++) r[o] = fmaxf(r[o], 0.f);

      float acc[48];
#pragma unroll
      for (int o = 0; o < 48; o++) acc[o] = W[OFF_B2 + o];
#pragma unroll 2
      for (int c = 0; c < 24; c++) {
#pragma unroll
        for (int o = 0; o < 48; o++) acc[o] = fmaf(W[OFF_W2 + c * 48 + o], r[c], acc[o]);
      }
#pragma unroll
      for (int op = 0; op < 24; op++) {
        __half2 u = Xh[s][op][tid];
        float xo0 = __low2float(u), xo1 = __high2float(u);
        float n0 = fmaxf(fmaf(W[OFF_XS + 2 * op], xo0, acc[2 * op]), 0.f);
        float n1 = fmaxf(fmaf(W[OFF_XS + 2 * op + 1], xo1, acc[2 * op + 1]), 0.f);
        Xh[s][op][tid] = __floats2half2_rn(n0, n1);
      }
    }

    // ---- k==0: la = emb(relu(cf @ concat(X0,X1))) ----
    if (k == 0) {
      float tv[48];
#pragma unroll
      for (int o = 0; o < 48; o++) tv[o] = W[OFF_BCF + o];
#pragma unroll 1
      for (int s = 0; s < 2; s++) {
#pragma unroll 2
        for (int cp = 0; cp < 24; cp++) {
          __half2 u = Xh[s][cp][tid];
          float x0c = __low2float(u), x1c = __high2float(u);
#pragma unroll
          for (int o = 0; o < 48; o++) {
            tv[o] = fmaf(W[OFF_WCF + (s * 48 + 2 * cp) * 48 + o], x0c, tv[o]);
            tv[o] = fmaf(W[OFF_WCF + (s * 48 + 2 * cp + 1) * 48 + o], x1c, tv[o]);
          }
        }
      }
#pragma unroll
      for (int o = 0; o < 48; o++) tv[o] = fmaxf(tv[o], 0.f);

      float h[24];
#pragma unroll
      for (int o = 0; o < 24; o++) h[o] = W[OFF_BE1 + o];
#pragma unroll 2
      for (int c = 0; c < 48; c++) {
#pragma unroll
        for (int o = 0; o < 24; o++) h[o] = fmaf(W[OFF_WE1 + c * 24 + o], tv[c], h[o]);
      }
#pragma unroll
      for (int o = 0; o < 24; o++) h[o] = gelu_f(h[o]);
#pragma unroll
      for (int o = 0; o < 48; o++) la[o] = W[OFF_BE2 + o];
#pragma unroll 2
      for (int c = 0; c < 24; c++) {
#pragma unroll
        for (int o = 0; o < 48; o++) la[o] = fmaf(W[OFF_WE2 + c * 48 + o], h[c], la[o]);
      }
    }

    // ---- kk1, kk2 from la (la dead afterwards) ----
    float kk1[24], kk2[24];
#pragma unroll
    for (int o = 0; o < 24; o++) { kk1[o] = W[OFF_BK1 + o]; kk2[o] = W[OFF_BK2 + o]; }
#pragma unroll 2
    for (int c = 0; c < 48; c++) {
      float lc = la[c];
#pragma unroll
      for (int o = 0; o < 24; o++) {
        kk1[o] = fmaf(W[OFF_WK1 + c * 24 + o], lc, kk1[o]);
        kk2[o] = fmaf(W[OFF_WK2 + c * 24 + o], lc, kk2[o]);
      }
    }

    // ---- scores: m order = {x0 lo, x0 hi, x1 lo, x1 hi} ----
    float s1[4], s2[4];
#pragma unroll
    for (int s = 0; s < 2; s++) {
      float q[48];
#pragma unroll
      for (int o = 0; o < 48; o++) q[o] = W[OFF_BQ + o];
#pragma unroll 2
      for (int cp = 0; cp < 24; cp++) {
        __half2 u = Xh[s][cp][tid];
        float x0c = __low2float(u), x1c = __high2float(u);
#pragma unroll
        for (int o = 0; o < 48; o++) {
          q[o] = fmaf(W[OFF_WQ + (2 * cp) * 48 + o], x0c, q[o]);
          q[o] = fmaf(W[OFF_WQ + (2 * cp + 1) * 48 + o], x1c, q[o]);
        }
      }
      float a10 = 0.f, a11 = 0.f, a20 = 0.f, a21 = 0.f;
#pragma unroll
      for (int o = 0; o < 24; o++) {
        a10 = fmaf(kk1[o], q[o], a10);
        a20 = fmaf(kk2[o], q[o], a20);
        a11 = fmaf(kk1[o], q[24 + o], a11);
        a21 = fmaf(kk2[o], q[24 + o], a21);
      }
      s1[2 * s] = a10; s1[2 * s + 1] = a11;
      s2[2 * s] = a20; s2[2 * s + 1] = a21;
    }
    // softmax over the 4 scores (per pixel)
    {
      float m1 = fmaxf(fmaxf(s1[0], s1[1]), fmaxf(s1[2], s1[3]));
      float e0 = __expf(s1[0] - m1), e1 = __expf(s1[1] - m1), e2 = __expf(s1[2] - m1), e3 = __expf(s1[3] - m1);
      float inv = 1.f / (e0 + e1 + e2 + e3);
      s1[0] = e0 * inv; s1[1] = e1 * inv; s1[2] = e2 * inv; s1[3] = e3 * inv;
      float m2 = fmaxf(fmaxf(s2[0], s2[1]), fmaxf(s2[2], s2[3]));
      float f0 = __expf(s2[0] - m2), f1 = __expf(s2[1] - m2), f2 = __expf(s2[2] - m2), f3 = __expf(s2[3] - m2);
      float jnv = 1.f / (f0 + f1 + f2 + f3);
      s2[0] = f0 * jnv; s2[1] = f1 * jnv; s2[2] = f2 * jnv; s2[3] = f3 * jnv;
    }

    // ---- values: r_j[c] = sum_m att_j[m] * v_m[c] ----
    float r1[24], r2[24];
#pragma unroll
    for (int o = 0; o < 24; o++) { r1[o] = 0.f; r2[o] = 0.f; }
#pragma unroll
    for (int s = 0; s < 2; s++) {
      float v[48];
#pragma unroll
      for (int o = 0; o < 48; o++) v[o] = W[OFF_BV + o];
#pragma unroll 2
      for (int cp = 0; cp < 24; cp++) {
        __half2 u = Xh[s][cp][tid];
        float x0c = __low2float(u), x1c = __high2float(u);
#pragma unroll
        for (int o = 0; o < 48; o++) {
          v[o] = fmaf(W[OFF_WV + (2 * cp) * 48 + o], x0c, v[o]);
          v[o] = fmaf(W[OFF_WV + (2 * cp + 1) * 48 + o], x1c, v[o]);
        }
      }
#pragma unroll
      for (int o = 0; o < 24; o++) {
        r1[o] = fmaf(s1[2 * s], v[o], r1[o]);
        r1[o] = fmaf(s1[2 * s + 1], v[24 + o], r1[o]);
        r2[o] = fmaf(s2[2 * s], v[o], r2[o]);
        r2[o] = fmaf(s2[2 * s + 1], v[24 + o], r2[o]);
      }
    }

    // ---- la = emb(concat(r1, r2)) ----
    {
      float h[24];
#pragma unroll
      for (int o = 0; o < 24; o++) h[o] = W[OFF_BE1 + o];
#pragma unroll 2
      for (int c = 0; c < 24; c++) {
#pragma unroll
        for (int o = 0; o < 24; o++) {
          h[o] = fmaf(W[OFF_WE1 + c * 24 + o], r1[c], h[o]);
          h[o] = fmaf(W[OFF_WE1 + (24 + c) * 24 + o], r2[c], h[o]);
        }
      }
#pragma unroll
      for (int o = 0; o < 24; o++) h[o] = gelu_f(h[o]);
#pragma unroll
      for (int o = 0; o < 48; o++) la[o] = W[OFF_BE2 + o];
#pragma unroll 2
      for (int c = 0; c < 24; c++) {
#pragma unroll
        for (int o = 0; o < 48; o++) la[o] = fmaf(W[OFF_WE2 + c * 48 + o], h[c], la[o]);
      }
    }
  }

  float* po = out + (size_t)b * 48 * HWS + n;
#pragma unroll 4
  for (int c = 0; c < 48; c++) po[(size_t)c * HWS] = la[c];
}

extern "C" void kernel_launch(void* const* d_in, const int* in_sizes, int n_in,
                              void* d_out, int out_size, void* d_ws, size_t ws_size,
                              hipStream_t stream) {
  PtrPack P;
  for (int i = 0; i < 48; i++) P.p[i] = (const float*)d_in[i];
  float* W = (float*)d_ws;

  fold_kernel<<<(WS_TOTAL + 255) / 256, 256, 0, stream>>>(P, W);
  fused_main<<<NPIX / T, T, 0, stream>>>(P.p[0], P.p[1], W, (float*)d_out);
}

// Round 7
// 1046.477 us; speedup vs baseline: 1.2052x; 1.2052x over previous
//
#include <hip/hip_runtime.h>
#include <hip/hip_fp16.h>
#include <stdint.h>
#include <math.h>

#define HWS 16384
#define NPIX (16 * HWS)
#define T 256

// float offsets into d_ws. All weight matrices stored TRANSPOSED: [cin][out],
// so c-outer/o-inner accumulation reads contiguous runs of `out` floats.
enum {
  OFF_W1  = 0,      // [48][24] rb conv1 (bn-folded)
  OFF_B1  = 1152,   // 24
  OFF_W2  = 1176,   // [24][48] rb conv2 (post-residual bn folded)
  OFF_B2  = 2328,   // 48
  OFF_XS  = 2376,   // 48  bn scale applied to xs in residual add
  OFF_WQ  = 2424,   // [48][48]
  OFF_BQ  = 4728,   // 48
  OFF_WV  = 4776,   // [48][48]
  OFF_BV  = 7080,   // 48
  OFF_WK1 = 7128,   // [48][24]
  OFF_BK1 = 8280,   // 24
  OFF_WK2 = 8304,   // [48][24]
  OFF_BK2 = 9456,   // 24
  OFF_WCF = 9480,   // [96][48]
  OFF_BCF = 14088,  // 48
  OFF_WE1 = 14136,  // [48][24] emb conv1 (no bn)
  OFF_BE1 = 15288,  // 24
  OFF_WE2 = 15312,  // [24][48]
  OFF_BE2 = 16464,  // 48
  WS_TOTAL = 16512
};

struct PtrPack { const float* p[48]; };

// bn fold: s = g/sqrt(v+eps), t = beta - m*s;  bn(conv(x,W,b)) = (s.W)x + (s.b + t)
#define SCALE_T(bnb, o, s, t)                                       \
  {                                                                 \
    float g_ = P.p[(bnb)][(o)], be_ = P.p[(bnb) + 1][(o)];          \
    float m_ = P.p[(bnb) + 2][(o)], v_ = P.p[(bnb) + 3][(o)];       \
    s = g_ / sqrtf(v_ + 1e-5f);                                     \
    t = be_ - m_ * s;                                               \
  }

__global__ void fold_kernel(PtrPack P, float* __restrict__ W) {
  int i = blockIdx.x * blockDim.x + threadIdx.x;
  float s, t;
  if (i < OFF_B1)        { int j = i;            int ci = j / 24, o = j % 24; SCALE_T(4,  o, s, t); W[i] = s * P.p[2][o * 48 + ci]; }
  else if (i < OFF_W2)   { int o = i - OFF_B1;                                SCALE_T(4,  o, s, t); W[i] = s * P.p[3][o] + t; }
  else if (i < OFF_B2)   { int j = i - OFF_W2;   int ci = j / 48, o = j % 48; SCALE_T(10, o, s, t); W[i] = s * P.p[8][o * 24 + ci]; }
  else if (i < OFF_XS)   { int o = i - OFF_B2;                                SCALE_T(10, o, s, t); W[i] = s * P.p[9][o] + t; }
  else if (i < OFF_WQ)   { int o = i - OFF_XS;                                SCALE_T(10, o, s, t); W[i] = s; }
  else if (i < OFF_BQ)   { int j = i - OFF_WQ;   int ci = j / 48, o = j % 48; SCALE_T(16, o, s, t); W[i] = s * P.p[14][o * 48 + ci]; }
  else if (i < OFF_WV)   { int o = i - OFF_BQ;                                SCALE_T(16, o, s, t); W[i] = s * P.p[15][o] + t; }
  else if (i < OFF_BV)   { int j = i - OFF_WV;   int ci = j / 48, o = j % 48; SCALE_T(22, o, s, t); W[i] = s * P.p[20][o * 48 + ci]; }
  else if (i < OFF_WK1)  { int o = i - OFF_BV;                                SCALE_T(22, o, s, t); W[i] = s * P.p[21][o] + t; }
  else if (i < OFF_BK1)  { int j = i - OFF_WK1;  int ci = j / 24, o = j % 24; SCALE_T(28, o, s, t); W[i] = s * P.p[26][o * 48 + ci]; }
  else if (i < OFF_WK2)  { int o = i - OFF_BK1;                               SCALE_T(28, o, s, t); W[i] = s * P.p[27][o] + t; }
  else if (i < OFF_BK2)  { int j = i - OFF_WK2;  int ci = j / 24, o = j % 24; SCALE_T(34, o, s, t); W[i] = s * P.p[32][o * 48 + ci]; }
  else if (i < OFF_WCF)  { int o = i - OFF_BK2;                               SCALE_T(34, o, s, t); W[i] = s * P.p[33][o] + t; }
  else if (i < OFF_BCF)  { int j = i - OFF_WCF;  int ci = j / 48, o = j % 48; SCALE_T(40, o, s, t); W[i] = s * P.p[38][o * 96 + ci]; }
  else if (i < OFF_WE1)  { int o = i - OFF_BCF;                               SCALE_T(40, o, s, t); W[i] = s * P.p[39][o] + t; }
  else if (i < OFF_BE1)  { int j = i - OFF_WE1;  int ci = j / 24, o = j % 24; W[i] = P.p[44][o * 48 + ci]; }
  else if (i < OFF_WE2)  { int o = i - OFF_BE1;  W[i] = P.p[45][o]; }
  else if (i < OFF_BE2)  { int j = i - OFF_WE2;  int ci = j / 48, o = j % 48; W[i] = P.p[46][o * 24 + ci]; }
  else if (i < WS_TOTAL) { int o = i - OFF_BE2;  W[i] = P.p[47][o]; }
}

// ---------------- fused per-pixel forward, X-state in LDS as fp16 pairs ----------------

__device__ __forceinline__ float gelu_f(float x) {
  return 0.5f * x * (1.f + erff(x * 0.70710678118654752440f));
}

__global__ __launch_bounds__(T)
void fused_main(const float* __restrict__ x0g,
                const float* __restrict__ x1g,
                const float* __restrict__ W,
                float* __restrict__ out) {
  // Per-thread private column of channel-pairs; [cp][tid] layout ->
  // lane-consecutive addresses, conflict-free, no cross-thread sharing.
  __shared__ __half2 Xh[2][24][T];
  const int tid = threadIdx.x;
  const int p = blockIdx.x * T + tid;
  const int b = p >> 14;  // hw = 16384
  const int n = p & (HWS - 1);

  {
    const float* px0 = x0g + (size_t)b * 48 * HWS + n;
    const float* px1 = x1g + (size_t)b * 48 * HWS + n;
#pragma unroll 4
    for (int cp = 0; cp < 24; cp++) {
      Xh[0][cp][tid] = __floats2half2_rn(px0[(size_t)(2 * cp) * HWS], px0[(size_t)(2 * cp + 1) * HWS]);
      Xh[1][cp][tid] = __floats2half2_rn(px1[(size_t)(2 * cp) * HWS], px1[(size_t)(2 * cp + 1) * HWS]);
    }
  }

  float la[48];

#pragma unroll 1
  for (int k = 0; k < 4; k++) {
    // ---- residual blocks (in-place on Xh), c-outer accumulation ----
#pragma unroll 1
    for (int s = 0; s < 2; s++) {
      float r[24];
#pragma unroll
      for (int o = 0; o < 24; o++) r[o] = W[OFF_B1 + o];
#pragma unroll 2
      for (int cp = 0; cp < 24; cp++) {
        __half2 u = Xh[s][cp][tid];
        float x0c = __low2float(u), x1c = __high2float(u);
#pragma unroll
        for (int o = 0; o < 24; o++) {
          r[o] = fmaf(W[OFF_W1 + (2 * cp) * 24 + o], x0c, r[o]);
          r[o] = fmaf(W[OFF_W1 + (2 * cp + 1) * 24 + o], x1c, r[o]);
        }
      }
#pragma unroll
      for (int o = 0; o < 24; o++) r[o] = fmaxf(r[o], 0.f);

      float acc[48];
#pragma unroll
      for (int o = 0; o < 48; o++) acc[o] = W[OFF_B2 + o];
#pragma unroll 2
      for (int c = 0; c < 24; c++) {
#pragma unroll
        for (int o = 0; o < 48; o++) acc[o] = fmaf(W[OFF_W2 + c * 48 + o], r[c], acc[o]);
      }
#pragma unroll
      for (int op = 0; op < 24; op++) {
        __half2 u = Xh[s][op][tid];
        float xo0 = __low2float(u), xo1 = __high2float(u);
        float n0 = fmaxf(fmaf(W[OFF_XS + 2 * op], xo0, acc[2 * op]), 0.f);
        float n1 = fmaxf(fmaf(W[OFF_XS + 2 * op + 1], xo1, acc[2 * op + 1]), 0.f);
        Xh[s][op][tid] = __floats2half2_rn(n0, n1);
      }
    }

    // ---- k==0: la = emb(relu(cf @ concat(X0,X1))) ----
    if (k == 0) {
      float tv[48];
#pragma unroll
      for (int o = 0; o < 48; o++) tv[o] = W[OFF_BCF + o];
#pragma unroll 1
      for (int s = 0; s < 2; s++) {
#pragma unroll 2
        for (int cp = 0; cp < 24; cp++) {
          __half2 u = Xh[s][cp][tid];
          float x0c = __low2float(u), x1c = __high2float(u);
#pragma unroll
          for (int o = 0; o < 48; o++) {
            tv[o] = fmaf(W[OFF_WCF + (s * 48 + 2 * cp) * 48 + o], x0c, tv[o]);
            tv[o] = fmaf(W[OFF_WCF + (s * 48 + 2 * cp + 1) * 48 + o], x1c, tv[o]);
          }
        }
      }
#pragma unroll
      for (int o = 0; o < 48; o++) tv[o] = fmaxf(tv[o], 0.f);

      float h[24];
#pragma unroll
      for (int o = 0; o < 24; o++) h[o] = W[OFF_BE1 + o];
#pragma unroll 2
      for (int c = 0; c < 48; c++) {
#pragma unroll
        for (int o = 0; o < 24; o++) h[o] = fmaf(W[OFF_WE1 + c * 24 + o], tv[c], h[o]);
      }
#pragma unroll
      for (int o = 0; o < 24; o++) h[o] = gelu_f(h[o]);
#pragma unroll
      for (int o = 0; o < 48; o++) la[o] = W[OFF_BE2 + o];
#pragma unroll 2
      for (int c = 0; c < 24; c++) {
#pragma unroll
        for (int o = 0; o < 48; o++) la[o] = fmaf(W[OFF_WE2 + c * 48 + o], h[c], la[o]);
      }
    }

    // ---- kk1, kk2 from la (la dead afterwards) ----
    float kk1[24], kk2[24];
#pragma unroll
    for (int o = 0; o < 24; o++) { kk1[o] = W[OFF_BK1 + o]; kk2[o] = W[OFF_BK2 + o]; }
#pragma unroll 2
    for (int c = 0; c < 48; c++) {
      float lc = la[c];
#pragma unroll
      for (int o = 0; o < 24; o++) {
        kk1[o] = fmaf(W[OFF_WK1 + c * 24 + o], lc, kk1[o]);
        kk2[o] = fmaf(W[OFF_WK2 + c * 24 + o], lc, kk2[o]);
      }
    }

    // ---- scores: m order = {x0 lo, x0 hi, x1 lo, x1 hi} ----
    float s1[4], s2[4];
#pragma unroll
    for (int s = 0; s < 2; s++) {
      float q[48];
#pragma unroll
      for (int o = 0; o < 48; o++) q[o] = W[OFF_BQ + o];
#pragma unroll 2
      for (int cp = 0; cp < 24; cp++) {
        __half2 u = Xh[s][cp][tid];
        float x0c = __low2float(u), x1c = __high2float(u);
#pragma unroll
        for (int o = 0; o < 48; o++) {
          q[o] = fmaf(W[OFF_WQ + (2 * cp) * 48 + o], x0c, q[o]);
          q[o] = fmaf(W[OFF_WQ + (2 * cp + 1) * 48 + o], x1c, q[o]);
        }
      }
      float a10 = 0.f, a11 = 0.f, a20 = 0.f, a21 = 0.f;
#pragma unroll
      for (int o = 0; o < 24; o++) {
        a10 = fmaf(kk1[o], q[o], a10);
        a20 = fmaf(kk2[o], q[o], a20);
        a11 = fmaf(kk1[o], q[24 + o], a11);
        a21 = fmaf(kk2[o], q[24 + o], a21);
      }
      s1[2 * s] = a10; s1[2 * s + 1] = a11;
      s2[2 * s] = a20; s2[2 * s + 1] = a21;
    }
    // softmax over the 4 scores (per pixel)
    {
      float m1 = fmaxf(fmaxf(s1[0], s1[1]), fmaxf(s1[2], s1[3]));
      float e0 = __expf(s1[0] - m1), e1 = __expf(s1[1] - m1), e2 = __expf(s1[2] - m1), e3 = __expf(s1[3] - m1);
      float inv = 1.f / (e0 + e1 + e2 + e3);
      s1[0] = e0 * inv; s1[1] = e1 * inv; s1[2] = e2 * inv; s1[3] = e3 * inv;
      float m2 = fmaxf(fmaxf(s2[0], s2[1]), fmaxf(s2[2], s2[3]));
      float f0 = __expf(s2[0] - m2), f1 = __expf(s2[1] - m2), f2 = __expf(s2[2] - m2), f3 = __expf(s2[3] - m2);
      float jnv = 1.f / (f0 + f1 + f2 + f3);
      s2[0] = f0 * jnv; s2[1] = f1 * jnv; s2[2] = f2 * jnv; s2[3] = f3 * jnv;
    }

    // ---- values: r_j[c] = sum_m att_j[m] * v_m[c] ----
    float r1[24], r2[24];
#pragma unroll
    for (int o = 0; o < 24; o++) { r1[o] = 0.f; r2[o] = 0.f; }
#pragma unroll
    for (int s = 0; s < 2; s++) {
      float v[48];
#pragma unroll
      for (int o = 0; o < 48; o++) v[o] = W[OFF_BV + o];
#pragma unroll 2
      for (int cp = 0; cp < 24; cp++) {
        __half2 u = Xh[s][cp][tid];
        float x0c = __low2float(u), x1c = __high2float(u);
#pragma unroll
        for (int o = 0; o < 48; o++) {
          v[o] = fmaf(W[OFF_WV + (2 * cp) * 48 + o], x0c, v[o]);
          v[o] = fmaf(W[OFF_WV + (2 * cp + 1) * 48 + o], x1c, v[o]);
        }
      }
#pragma unroll
      for (int o = 0; o < 24; o++) {
        r1[o] = fmaf(s1[2 * s], v[o], r1[o]);
        r1[o] = fmaf(s1[2 * s + 1], v[24 + o], r1[o]);
        r2[o] = fmaf(s2[2 * s], v[o], r2[o]);
        r2[o] = fmaf(s2[2 * s + 1], v[24 + o], r2[o]);
      }
    }

    // ---- la = emb(concat(r1, r2)) ----
    {
      float h[24];
#pragma unroll
      for (int o = 0; o < 24; o++) h[o] = W[OFF_BE1 + o];
#pragma unroll 2
      for (int c = 0; c < 24; c++) {
#pragma unroll
        for (int o = 0; o < 24; o++) {
          h[o] = fmaf(W[OFF_WE1 + c * 24 + o], r1[c], h[o]);
          h[o] = fmaf(W[OFF_WE1 + (24 + c) * 24 + o], r2[c], h[o]);
        }
      }
#pragma unroll
      for (int o = 0; o < 24; o++) h[o] = gelu_f(h[o]);
#pragma unroll
      for (int o = 0; o < 48; o++) la[o] = W[OFF_BE2 + o];
#pragma unroll 2
      for (int c = 0; c < 24; c++) {
#pragma unroll
        for (int o = 0; o < 48; o++) la[o] = fmaf(W[OFF_WE2 + c * 48 + o], h[c], la[o]);
      }
    }
  }

  float* po = out + (size_t)b * 48 * HWS + n;
#pragma unroll 4
  for (int c = 0; c < 48; c++) po[(size_t)c * HWS] = la[c];
}

extern "C" void kernel_launch(void* const* d_in, const int* in_sizes, int n_in,
                              void* d_out, int out_size, void* d_ws, size_t ws_size,
                              hipStream_t stream) {
  PtrPack P;
  for (int i = 0; i < 48; i++) P.p[i] = (const float*)d_in[i];
  float* W = (float*)d_ws;

  fold_kernel<<<(WS_TOTAL + 255) / 256, 256, 0, stream>>>(P, W);
  fused_main<<<NPIX / T, T, 0, stream>>>(P.p[0], P.p[1], W, (float*)d_out);
}

// Round 8
// 1027.632 us; speedup vs baseline: 1.2273x; 1.0183x over previous
//
#include <hip/hip_runtime.h>
#include <hip/hip_fp16.h>
#include <stdint.h>
#include <math.h>

#define HWS 16384
#define NPIX (16 * HWS)
#define T 256

// float offsets into d_ws. Weight matrices stored TRANSPOSED: [cin][out].
// K1F/K2F are the WE2-folded key convs: kk = K_f . h  (h = gelu(emb1 out)).
enum {
  OFF_W1  = 0,      // [48][24] rb conv1 (bn-folded)
  OFF_B1  = 1152,   // 24
  OFF_W2  = 1176,   // [24][48] rb conv2 (post-residual bn folded)
  OFF_B2  = 2328,   // 48
  OFF_XS  = 2376,   // 48  bn scale applied to xs in residual add
  OFF_WQ  = 2424,   // [48][48]
  OFF_BQ  = 4728,   // 48
  OFF_WV  = 4776,   // [48][48]
  OFF_BV  = 7080,   // 48
  OFF_K1F = 7128,   // [24][24]  (s1.Wk1).WE2 transposed
  OFF_B1F = 7704,   // 24        s1.(Wk1.be2 + bk1) + t1
  OFF_K2F = 7728,   // [24][24]
  OFF_B2F = 8304,   // 24
  OFF_WCF = 8328,   // [96][48]
  OFF_BCF = 12936,  // 48
  OFF_WE1 = 12984,  // [48][24] emb conv1 (no bn)
  OFF_BE1 = 14136,  // 24
  OFF_WE2 = 14160,  // [24][48] emb conv2 (final output only)
  OFF_BE2 = 15312,  // 48
  WS_TOTAL = 15360
};

struct PtrPack { const float* p[48]; };

// bn fold: s = g/sqrt(v+eps), t = beta - m*s;  bn(conv(x,W,b)) = (s.W)x + (s.b + t)
#define SCALE_T(bnb, o, s, t)                                       \
  {                                                                 \
    float g_ = P.p[(bnb)][(o)], be_ = P.p[(bnb) + 1][(o)];          \
    float m_ = P.p[(bnb) + 2][(o)], v_ = P.p[(bnb) + 3][(o)];       \
    s = g_ / sqrtf(v_ + 1e-5f);                                     \
    t = be_ - m_ * s;                                               \
  }

__global__ void fold_kernel(PtrPack P, float* __restrict__ W) {
  int i = blockIdx.x * blockDim.x + threadIdx.x;
  float s, t;
  if (i < OFF_B1)        { int j = i;            int ci = j / 24, o = j % 24; SCALE_T(4,  o, s, t); W[i] = s * P.p[2][o * 48 + ci]; }
  else if (i < OFF_W2)   { int o = i - OFF_B1;                                SCALE_T(4,  o, s, t); W[i] = s * P.p[3][o] + t; }
  else if (i < OFF_B2)   { int j = i - OFF_W2;   int ci = j / 48, o = j % 48; SCALE_T(10, o, s, t); W[i] = s * P.p[8][o * 24 + ci]; }
  else if (i < OFF_XS)   { int o = i - OFF_B2;                                SCALE_T(10, o, s, t); W[i] = s * P.p[9][o] + t; }
  else if (i < OFF_WQ)   { int o = i - OFF_XS;                                SCALE_T(10, o, s, t); W[i] = s; }
  else if (i < OFF_BQ)   { int j = i - OFF_WQ;   int ci = j / 48, o = j % 48; SCALE_T(16, o, s, t); W[i] = s * P.p[14][o * 48 + ci]; }
  else if (i < OFF_WV)   { int o = i - OFF_BQ;                                SCALE_T(16, o, s, t); W[i] = s * P.p[15][o] + t; }
  else if (i < OFF_BV)   { int j = i - OFF_WV;   int ci = j / 48, o = j % 48; SCALE_T(22, o, s, t); W[i] = s * P.p[20][o * 48 + ci]; }
  else if (i < OFF_K1F)  { int o = i - OFF_BV;                                SCALE_T(22, o, s, t); W[i] = s * P.p[21][o] + t; }
  else if (i < OFF_B1F)  { int j = i - OFF_K1F;  int hh = j / 24, o = j % 24; SCALE_T(28, o, s, t);
                           float a = 0.f;
                           for (int c = 0; c < 48; c++) a += P.p[26][o * 48 + c] * P.p[46][c * 24 + hh];
                           W[i] = s * a; }
  else if (i < OFF_K2F)  { int o = i - OFF_B1F;                               SCALE_T(28, o, s, t);
                           float a = P.p[27][o];
                           for (int c = 0; c < 48; c++) a += P.p[26][o * 48 + c] * P.p[47][c];
                           W[i] = s * a + t; }
  else if (i < OFF_B2F)  { int j = i - OFF_K2F;  int hh = j / 24, o = j % 24; SCALE_T(34, o, s, t);
                           float a = 0.f;
                           for (int c = 0; c < 48; c++) a += P.p[32][o * 48 + c] * P.p[46][c * 24 + hh];
                           W[i] = s * a; }
  else if (i < OFF_WCF)  { int o = i - OFF_B2F;                               SCALE_T(34, o, s, t);
                           float a = P.p[33][o];
                           for (int c = 0; c < 48; c++) a += P.p[32][o * 48 + c] * P.p[47][c];
                           W[i] = s * a + t; }
  else if (i < OFF_BCF)  { int j = i - OFF_WCF;  int ci = j / 48, o = j % 48; SCALE_T(40, o, s, t); W[i] = s * P.p[38][o * 96 + ci]; }
  else if (i < OFF_WE1)  { int o = i - OFF_BCF;                               SCALE_T(40, o, s, t); W[i] = s * P.p[39][o] + t; }
  else if (i < OFF_BE1)  { int j = i - OFF_WE1;  int ci = j / 24, o = j % 24; W[i] = P.p[44][o * 48 + ci]; }
  else if (i < OFF_WE2)  { int o = i - OFF_BE1;  W[i] = P.p[45][o]; }
  else if (i < OFF_BE2)  { int j = i - OFF_WE2;  int hh = j / 48, o = j % 48; W[i] = P.p[46][o * 24 + hh]; }
  else if (i < WS_TOTAL) { int o = i - OFF_BE2;  W[i] = P.p[47][o]; }
}

// ---------------- fused per-pixel forward, X-state in LDS as fp16 pairs ----------------

__device__ __forceinline__ float gelu_f(float x) {
  return 0.5f * x * (1.f + erff(x * 0.70710678118654752440f));
}

__global__ __launch_bounds__(T)
void fused_main(const float* __restrict__ x0g,
                const float* __restrict__ x1g,
                const float* __restrict__ W,
                float* __restrict__ out) {
  // Per-thread private column of channel-pairs; [cp][tid] layout ->
  // lane-consecutive addresses, conflict-free, no cross-thread sharing.
  __shared__ __half2 Xh[2][24][T];
  const int tid = threadIdx.x;
  const int p = blockIdx.x * T + tid;
  const int b = p >> 14;  // hw = 16384
  const int n = p & (HWS - 1);

  {
    const float* px0 = x0g + (size_t)b * 48 * HWS + n;
    const float* px1 = x1g + (size_t)b * 48 * HWS + n;
#pragma unroll 4
    for (int cp = 0; cp < 24; cp++) {
      Xh[0][cp][tid] = __floats2half2_rn(px0[(size_t)(2 * cp) * HWS], px0[(size_t)(2 * cp + 1) * HWS]);
      Xh[1][cp][tid] = __floats2half2_rn(px1[(size_t)(2 * cp) * HWS], px1[(size_t)(2 * cp + 1) * HWS]);
    }
  }

  float h[24];  // gelu'd emb1 output — the la-carrier across iterations

#pragma unroll 1
  for (int k = 0; k < 4; k++) {
    // ---- residual blocks (in-place on Xh); acc in o-halves ----
#pragma unroll 1
    for (int s = 0; s < 2; s++) {
      float r[24];
#pragma unroll
      for (int o = 0; o < 24; o++) r[o] = W[OFF_B1 + o];
#pragma unroll 2
      for (int cp = 0; cp < 24; cp++) {
        __half2 u = Xh[s][cp][tid];
        float x0c = __low2float(u), x1c = __high2float(u);
#pragma unroll
        for (int o = 0; o < 24; o++) {
          r[o] = fmaf(W[OFF_W1 + (2 * cp) * 24 + o], x0c, r[o]);
          r[o] = fmaf(W[OFF_W1 + (2 * cp + 1) * 24 + o], x1c, r[o]);
        }
      }
#pragma unroll
      for (int o = 0; o < 24; o++) r[o] = fmaxf(r[o], 0.f);

#pragma unroll 1
      for (int hf = 0; hf < 2; hf++) {
        float acc[24];
#pragma unroll
        for (int o = 0; o < 24; o++) acc[o] = W[OFF_B2 + hf * 24 + o];
#pragma unroll 2
        for (int c = 0; c < 24; c++) {
#pragma unroll
          for (int o = 0; o < 24; o++) acc[o] = fmaf(W[OFF_W2 + c * 48 + hf * 24 + o], r[c], acc[o]);
        }
#pragma unroll
        for (int op = 0; op < 12; op++) {
          __half2 u = Xh[s][hf * 12 + op][tid];
          float xo0 = __low2float(u), xo1 = __high2float(u);
          float n0 = fmaxf(fmaf(W[OFF_XS + hf * 24 + 2 * op], xo0, acc[2 * op]), 0.f);
          float n1 = fmaxf(fmaf(W[OFF_XS + hf * 24 + 2 * op + 1], xo1, acc[2 * op + 1]), 0.f);
          Xh[s][hf * 12 + op][tid] = __floats2half2_rn(n0, n1);
        }
      }
    }

    // ---- k==0: h = gelu(WE1 . relu(cf @ concat(X0,X1)) + BE1) ----
    if (k == 0) {
      float tv[48];
#pragma unroll
      for (int o = 0; o < 48; o++) tv[o] = W[OFF_BCF + o];
#pragma unroll 1
      for (int s = 0; s < 2; s++) {
#pragma unroll 2
        for (int cp = 0; cp < 24; cp++) {
          __half2 u = Xh[s][cp][tid];
          float x0c = __low2float(u), x1c = __high2float(u);
#pragma unroll
          for (int o = 0; o < 48; o++) {
            tv[o] = fmaf(W[OFF_WCF + (s * 48 + 2 * cp) * 48 + o], x0c, tv[o]);
            tv[o] = fmaf(W[OFF_WCF + (s * 48 + 2 * cp + 1) * 48 + o], x1c, tv[o]);
          }
        }
      }
#pragma unroll
      for (int o = 0; o < 48; o++) tv[o] = fmaxf(tv[o], 0.f);
#pragma unroll
      for (int o = 0; o < 24; o++) h[o] = W[OFF_BE1 + o];
#pragma unroll 2
      for (int c = 0; c < 48; c++) {
#pragma unroll
        for (int o = 0; o < 24; o++) h[o] = fmaf(W[OFF_WE1 + c * 24 + o], tv[c], h[o]);
      }
#pragma unroll
      for (int o = 0; o < 24; o++) h[o] = gelu_f(h[o]);
    }

    // ---- kk1, kk2 from h (WE2-folded; h dead afterwards) ----
    float kk1[24], kk2[24];
#pragma unroll
    for (int o = 0; o < 24; o++) { kk1[o] = W[OFF_B1F + o]; kk2[o] = W[OFF_B2F + o]; }
#pragma unroll 2
    for (int c = 0; c < 24; c++) {
      float hc = h[c];
#pragma unroll
      for (int o = 0; o < 24; o++) {
        kk1[o] = fmaf(W[OFF_K1F + c * 24 + o], hc, kk1[o]);
        kk2[o] = fmaf(W[OFF_K2F + c * 24 + o], hc, kk2[o]);
      }
    }

    // ---- scores (q in o-halves): m order = {x0 lo, x0 hi, x1 lo, x1 hi} ----
    float s1[4], s2[4];
#pragma unroll
    for (int s = 0; s < 2; s++) {
#pragma unroll
      for (int qh = 0; qh < 2; qh++) {
        float q[24];
#pragma unroll
        for (int o = 0; o < 24; o++) q[o] = W[OFF_BQ + qh * 24 + o];
#pragma unroll 2
        for (int cp = 0; cp < 24; cp++) {
          __half2 u = Xh[s][cp][tid];
          float x0c = __low2float(u), x1c = __high2float(u);
#pragma unroll
          for (int o = 0; o < 24; o++) {
            q[o] = fmaf(W[OFF_WQ + (2 * cp) * 48 + qh * 24 + o], x0c, q[o]);
            q[o] = fmaf(W[OFF_WQ + (2 * cp + 1) * 48 + qh * 24 + o], x1c, q[o]);
          }
        }
        float a1 = 0.f, a2 = 0.f;
#pragma unroll
        for (int o = 0; o < 24; o++) {
          a1 = fmaf(kk1[o], q[o], a1);
          a2 = fmaf(kk2[o], q[o], a2);
        }
        s1[2 * s + qh] = a1;
        s2[2 * s + qh] = a2;
      }
    }
    // softmax over the 4 scores (per pixel)
    {
      float m1 = fmaxf(fmaxf(s1[0], s1[1]), fmaxf(s1[2], s1[3]));
      float e0 = __expf(s1[0] - m1), e1 = __expf(s1[1] - m1), e2 = __expf(s1[2] - m1), e3 = __expf(s1[3] - m1);
      float inv = 1.f / (e0 + e1 + e2 + e3);
      s1[0] = e0 * inv; s1[1] = e1 * inv; s1[2] = e2 * inv; s1[3] = e3 * inv;
      float m2 = fmaxf(fmaxf(s2[0], s2[1]), fmaxf(s2[2], s2[3]));
      float f0 = __expf(s2[0] - m2), f1 = __expf(s2[1] - m2), f2 = __expf(s2[2] - m2), f3 = __expf(s2[3] - m2);
      float jnv = 1.f / (f0 + f1 + f2 + f3);
      s2[0] = f0 * jnv; s2[1] = f1 * jnv; s2[2] = f2 * jnv; s2[3] = f3 * jnv;
    }

    // ---- values (v in o-halves): r_j[c] = sum_m att_j[m] * v_m[c] ----
    float r1[24], r2[24];
#pragma unroll
    for (int o = 0; o < 24; o++) { r1[o] = 0.f; r2[o] = 0.f; }
#pragma unroll
    for (int s = 0; s < 2; s++) {
#pragma unroll
      for (int vh = 0; vh < 2; vh++) {
        float v[24];
#pragma unroll
        for (int o = 0; o < 24; o++) v[o] = W[OFF_BV + vh * 24 + o];
#pragma unroll 2
        for (int cp = 0; cp < 24; cp++) {
          __half2 u = Xh[s][cp][tid];
          float x0c = __low2float(u), x1c = __high2float(u);
#pragma unroll
          for (int o = 0; o < 24; o++) {
            v[o] = fmaf(W[OFF_WV + (2 * cp) * 48 + vh * 24 + o], x0c, v[o]);
            v[o] = fmaf(W[OFF_WV + (2 * cp + 1) * 48 + vh * 24 + o], x1c, v[o]);
          }
        }
        float w1 = s1[2 * s + vh], w2 = s2[2 * s + vh];
#pragma unroll
        for (int o = 0; o < 24; o++) {
          r1[o] = fmaf(w1, v[o], r1[o]);
          r2[o] = fmaf(w2, v[o], r2[o]);
        }
      }
    }

    // ---- h = gelu(WE1 . concat(r1, r2) + BE1) ----
#pragma unroll
    for (int o = 0; o < 24; o++) h[o] = W[OFF_BE1 + o];
#pragma unroll 2
    for (int c = 0; c < 24; c++) {
#pragma unroll
      for (int o = 0; o < 24; o++) {
        h[o] = fmaf(W[OFF_WE1 + c * 24 + o], r1[c], h[o]);
        h[o] = fmaf(W[OFF_WE1 + (24 + c) * 24 + o], r2[c], h[o]);
      }
    }
#pragma unroll
    for (int o = 0; o < 24; o++) h[o] = gelu_f(h[o]);
  }

  // ---- final: la = WE2 . h + BE2, in o-halves; write out ----
  float* po = out + (size_t)b * 48 * HWS + n;
#pragma unroll 1
  for (int hf = 0; hf < 2; hf++) {
    float la[24];
#pragma unroll
    for (int o = 0; o < 24; o++) la[o] = W[OFF_BE2 + hf * 24 + o];
#pragma unroll 2
    for (int c = 0; c < 24; c++) {
#pragma unroll
      for (int o = 0; o < 24; o++) la[o] = fmaf(W[OFF_WE2 + c * 48 + hf * 24 + o], h[c], la[o]);
    }
#pragma unroll
    for (int o = 0; o < 24; o++) po[(size_t)(hf * 24 + o) * HWS] = la[o];
  }
}

extern "C" void kernel_launch(void* const* d_in, const int* in_sizes, int n_in,
                              void* d_out, int out_size, void* d_ws, size_t ws_size,
                              hipStream_t stream) {
  PtrPack P;
  for (int i = 0; i < 48; i++) P.p[i] = (const float*)d_in[i];
  float* W = (float*)d_ws;

  fold_kernel<<<(WS_TOTAL + 255) / 256, 256, 0, stream>>>(P, W);
  fused_main<<<NPIX / T, T, 0, stream>>>(P.p[0], P.p[1], W, (float*)d_out);
}

// Round 9
// 810.290 us; speedup vs baseline: 1.5565x; 1.2682x over previous
//
#include <hip/hip_runtime.h>
#include <hip/hip_fp16.h>
#include <stdint.h>
#include <math.h>

#define HWS 16384
#define NPIX (16 * HWS)
#define T 256

// Folded fp32 table in d_ws (float offsets). Layouts chosen so every rolled
// loop reads contiguous rows.
enum {
  OFF_W1T  = 0,      // [48][24] c-major: rb conv1 (bn-folded)
  OFF_B1   = 1152,   // 24
  OFF_W2R  = 1176,   // [48][24] o-major rows: rb conv2
  OFF_B2   = 2328,   // 48
  OFF_XS   = 2376,   // 48
  OFF_M1A  = 2424,   // [48][24] c-major: score fold kk1/qh0
  OFF_M1B  = 3576,   // kk1/qh1
  OFF_M2A  = 4728,   // kk2/qh0
  OFF_M2B  = 5880,   // kk2/qh1
  OFF_C1A  = 7032,   // 48 each
  OFF_C1B  = 7080,
  OFF_C2A  = 7128,
  OFF_C2B  = 7176,
  OFF_D1A  = 7224,   // 24 each
  OFF_D1B  = 7248,
  OFF_D2A  = 7272,
  OFF_D2B  = 7296,
  OFF_E4   = 7320,   // 4 scalars e1a,e1b,e2a,e2b
  OFF_P1L  = 7324,   // [48][24] c-major: value->emb1 fold
  OFF_P1H  = 8476,
  OFF_P2L  = 9628,
  OFF_P2H  = 10780,
  OFF_Q1L  = 11932,  // 24 each (value-bias through WE1)
  OFF_Q1H  = 11956,
  OFF_Q2L  = 11980,
  OFF_Q2H  = 12004,
  OFF_BE1  = 12028,  // 24
  OFF_CFT  = 12052,  // [96][48] cin-major
  OFF_BCF  = 16660,  // 48
  OFF_WE1  = 16708,  // [24][48] o-major (k0 emb only)
  OFF_BE2  = 17860,  // 48
  OFF_WE2R = 17908,  // [48][24] o-major
  WS_TOTAL = 19060
};

struct PtrPack { const float* p[48]; };

__device__ __forceinline__ void bnst(const PtrPack& P, int bnb, int o, float& s, float& t) {
  float g = P.p[bnb][o], be = P.p[bnb + 1][o], m = P.p[bnb + 2][o], v = P.p[bnb + 3][o];
  s = g / sqrtf(v + 1e-5f);
  t = be - m * s;
}
// K-fold through WE2: K[ok][j] = s_k[ok] * sum_cc k_w[ok][cc] * we2[cc][j]
__device__ __forceinline__ float KFv(const PtrPack& P, const float* kw, int bnb, int ok, int j) {
  float s, t; bnst(P, bnb, ok, s, t);
  float a = 0.f;
  for (int cc = 0; cc < 48; cc++) a += kw[ok * 48 + cc] * P.p[46][cc * 24 + j];
  return s * a;
}
// K bias: s_k*(k_w . be2 + k_b) + t_k
__device__ __forceinline__ float BFv(const PtrPack& P, const float* kw, const float* kb, int bnb, int ok) {
  float s, t; bnst(P, bnb, ok, s, t);
  float a = kb[ok];
  for (int cc = 0; cc < 48; cc++) a += kw[ok * 48 + cc] * P.p[47][cc];
  return s * a + t;
}
__device__ __forceinline__ float WQf(const PtrPack& P, int o, int c) { float s, t; bnst(P, 16, o, s, t); return s * P.p[14][o * 48 + c]; }
__device__ __forceinline__ float BQf(const PtrPack& P, int o) { float s, t; bnst(P, 16, o, s, t); return s * P.p[15][o] + t; }
__device__ __forceinline__ float WVf(const PtrPack& P, int o, int c) { float s, t; bnst(P, 22, o, s, t); return s * P.p[20][o * 48 + c]; }
__device__ __forceinline__ float BVf(const PtrPack& P, int o) { float s, t; bnst(P, 22, o, s, t); return s * P.p[21][o] + t; }

__global__ void fold_kernel(PtrPack P, float* __restrict__ W) {
  int i = blockIdx.x * blockDim.x + threadIdx.x;
  if (i >= WS_TOTAL) return;
  float s, t, a;
  if (i < OFF_B1) { int c = i / 24, o = i % 24; bnst(P, 4, o, s, t); W[i] = s * P.p[2][o * 48 + c]; }
  else if (i < OFF_W2R) { int o = i - OFF_B1; bnst(P, 4, o, s, t); W[i] = s * P.p[3][o] + t; }
  else if (i < OFF_B2)  { int j = i - OFF_W2R; int o = j / 24, c = j % 24; bnst(P, 10, o, s, t); W[i] = s * P.p[8][o * 24 + c]; }
  else if (i < OFF_XS)  { int o = i - OFF_B2; bnst(P, 10, o, s, t); W[i] = s * P.p[9][o] + t; }
  else if (i < OFF_M1A) { int o = i - OFF_XS; bnst(P, 10, o, s, t); W[i] = s; }
  else if (i < OFF_M1B) { int j = i - OFF_M1A; int c = j / 24, jj = j % 24; a = 0.f;
    for (int ok = 0; ok < 24; ok++) a += KFv(P, P.p[26], 28, ok, jj) * WQf(P, ok, c); W[i] = a; }
  else if (i < OFF_M2A) { int j = i - OFF_M1B; int c = j / 24, jj = j % 24; a = 0.f;
    for (int ok = 0; ok < 24; ok++) a += KFv(P, P.p[26], 28, ok, jj) * WQf(P, 24 + ok, c); W[i] = a; }
  else if (i < OFF_M2B) { int j = i - OFF_M2A; int c = j / 24, jj = j % 24; a = 0.f;
    for (int ok = 0; ok < 24; ok++) a += KFv(P, P.p[32], 34, ok, jj) * WQf(P, ok, c); W[i] = a; }
  else if (i < OFF_C1A) { int j = i - OFF_M2B; int c = j / 24, jj = j % 24; a = 0.f;
    for (int ok = 0; ok < 24; ok++) a += KFv(P, P.p[32], 34, ok, jj) * WQf(P, 24 + ok, c); W[i] = a; }
  else if (i < OFF_C1B) { int c = i - OFF_C1A; a = 0.f;
    for (int ok = 0; ok < 24; ok++) a += BFv(P, P.p[26], P.p[27], 28, ok) * WQf(P, ok, c); W[i] = a; }
  else if (i < OFF_C2A) { int c = i - OFF_C1B; a = 0.f;
    for (int ok = 0; ok < 24; ok++) a += BFv(P, P.p[26], P.p[27], 28, ok) * WQf(P, 24 + ok, c); W[i] = a; }
  else if (i < OFF_C2B) { int c = i - OFF_C2A; a = 0.f;
    for (int ok = 0; ok < 24; ok++) a += BFv(P, P.p[32], P.p[33], 34, ok) * WQf(P, ok, c); W[i] = a; }
  else if (i < OFF_D1A) { int c = i - OFF_C2B; a = 0.f;
    for (int ok = 0; ok < 24; ok++) a += BFv(P, P.p[32], P.p[33], 34, ok) * WQf(P, 24 + ok, c); W[i] = a; }
  else if (i < OFF_D1B) { int jj = i - OFF_D1A; a = 0.f;
    for (int ok = 0; ok < 24; ok++) a += KFv(P, P.p[26], 28, ok, jj) * BQf(P, ok); W[i] = a; }
  else if (i < OFF_D2A) { int jj = i - OFF_D1B; a = 0.f;
    for (int ok = 0; ok < 24; ok++) a += KFv(P, P.p[26], 28, ok, jj) * BQf(P, 24 + ok); W[i] = a; }
  else if (i < OFF_D2B) { int jj = i - OFF_D2A; a = 0.f;
    for (int ok = 0; ok < 24; ok++) a += KFv(P, P.p[32], 34, ok, jj) * BQf(P, ok); W[i] = a; }
  else if (i < OFF_E4)  { int jj = i - OFF_D2B; a = 0.f;
    for (int ok = 0; ok < 24; ok++) a += KFv(P, P.p[32], 34, ok, jj) * BQf(P, 24 + ok); W[i] = a; }
  else if (i < OFF_P1L) { int e = i - OFF_E4; a = 0.f;
    if (e == 0)      for (int ok = 0; ok < 24; ok++) a += BFv(P, P.p[26], P.p[27], 28, ok) * BQf(P, ok);
    else if (e == 1) for (int ok = 0; ok < 24; ok++) a += BFv(P, P.p[26], P.p[27], 28, ok) * BQf(P, 24 + ok);
    else if (e == 2) for (int ok = 0; ok < 24; ok++) a += BFv(P, P.p[32], P.p[33], 34, ok) * BQf(P, ok);
    else             for (int ok = 0; ok < 24; ok++) a += BFv(P, P.p[32], P.p[33], 34, ok) * BQf(P, 24 + ok);
    W[i] = a; }
  else if (i < OFF_P1H) { int j = i - OFF_P1L; int c = j / 24, o = j % 24; a = 0.f;
    for (int jj = 0; jj < 24; jj++) a += P.p[44][o * 48 + jj] * WVf(P, jj, c); W[i] = a; }
  else if (i < OFF_P2L) { int j = i - OFF_P1H; int c = j / 24, o = j % 24; a = 0.f;
    for (int jj = 0; jj < 24; jj++) a += P.p[44][o * 48 + jj] * WVf(P, 24 + jj, c); W[i] = a; }
  else if (i < OFF_P2H) { int j = i - OFF_P2L; int c = j / 24, o = j % 24; a = 0.f;
    for (int jj = 0; jj < 24; jj++) a += P.p[44][o * 48 + 24 + jj] * WVf(P, jj, c); W[i] = a; }
  else if (i < OFF_Q1L) { int j = i - OFF_P2H; int c = j / 24, o = j % 24; a = 0.f;
    for (int jj = 0; jj < 24; jj++) a += P.p[44][o * 48 + 24 + jj] * WVf(P, 24 + jj, c); W[i] = a; }
  else if (i < OFF_Q1H) { int o = i - OFF_Q1L; a = 0.f;
    for (int jj = 0; jj < 24; jj++) a += P.p[44][o * 48 + jj] * BVf(P, jj); W[i] = a; }
  else if (i < OFF_Q2L) { int o = i - OFF_Q1H; a = 0.f;
    for (int jj = 0; jj < 24; jj++) a += P.p[44][o * 48 + jj] * BVf(P, 24 + jj); W[i] = a; }
  else if (i < OFF_Q2H) { int o = i - OFF_Q2L; a = 0.f;
    for (int jj = 0; jj < 24; jj++) a += P.p[44][o * 48 + 24 + jj] * BVf(P, jj); W[i] = a; }
  else if (i < OFF_BE1) { int o = i - OFF_Q2H; a = 0.f;
    for (int jj = 0; jj < 24; jj++) a += P.p[44][o * 48 + 24 + jj] * BVf(P, 24 + jj); W[i] = a; }
  else if (i < OFF_CFT) { int o = i - OFF_BE1; W[i] = P.p[45][o]; }
  else if (i < OFF_BCF) { int j = i - OFF_CFT; int cin = j / 48, o = j % 48; bnst(P, 40, o, s, t); W[i] = s * P.p[38][o * 96 + cin]; }
  else if (i < OFF_WE1) { int o = i - OFF_BCF; bnst(P, 40, o, s, t); W[i] = s * P.p[39][o] + t; }
  else if (i < OFF_BE2) { int j = i - OFF_WE1; W[i] = P.p[44][j]; }
  else if (i < OFF_WE2R){ int o = i - OFF_BE2; W[i] = P.p[47][o]; }
  else                  { int j = i - OFF_WE2R; W[i] = P.p[46][j]; }
}

// ---------------- fused per-pixel forward ----------------

__device__ __forceinline__ float gelu_f(float x) {
  return 0.5f * x * (1.f + erff(x * 0.70710678118654752440f));
}

__global__ __launch_bounds__(T)
void fused_main(const float* __restrict__ x0g,
                const float* __restrict__ x1g,
                const float* __restrict__ W,
                float* __restrict__ out) {
  __shared__ __half2 Xh[2][24][T];
  const int tid = threadIdx.x;
  const int p = blockIdx.x * T + tid;
  const int b = p >> 14;
  const int n = p & (HWS - 1);

  {
    const float* px0 = x0g + (size_t)b * 48 * HWS + n;
    const float* px1 = x1g + (size_t)b * 48 * HWS + n;
#pragma unroll 1
    for (int cp = 0; cp < 24; cp++) {
      Xh[0][cp][tid] = __floats2half2_rn(px0[(size_t)(2 * cp) * HWS], px0[(size_t)(2 * cp + 1) * HWS]);
      Xh[1][cp][tid] = __floats2half2_rn(px1[(size_t)(2 * cp) * HWS], px1[(size_t)(2 * cp + 1) * HWS]);
    }
  }

  float h[24];

#pragma unroll 1
  for (int k = 0; k < 4; k++) {
    // ---- residual blocks ----
#pragma unroll 1
    for (int s = 0; s < 2; s++) {
      float r[24];
#pragma unroll
      for (int o = 0; o < 24; o++) r[o] = W[OFF_B1 + o];
#pragma unroll 1
      for (int cp = 0; cp < 24; cp++) {
        __half2 u = Xh[s][cp][tid];
        float x0c = __low2float(u), x1c = __high2float(u);
        const float* w0 = &W[OFF_W1T + (2 * cp) * 24];
#pragma unroll
        for (int o = 0; o < 24; o++) r[o] = fmaf(w0[o], x0c, r[o]);
#pragma unroll
        for (int o = 0; o < 24; o++) r[o] = fmaf(w0[24 + o], x1c, r[o]);
      }
#pragma unroll
      for (int o = 0; o < 24; o++) r[o] = fmaxf(r[o], 0.f);

#pragma unroll 1
      for (int op = 0; op < 24; op++) {
        const float* w0 = &W[OFF_W2R + (2 * op) * 24];
        float a0 = W[OFF_B2 + 2 * op], a1 = W[OFF_B2 + 2 * op + 1];
#pragma unroll
        for (int c = 0; c < 24; c++) a0 = fmaf(w0[c], r[c], a0);
#pragma unroll
        for (int c = 0; c < 24; c++) a1 = fmaf(w0[24 + c], r[c], a1);
        __half2 u = Xh[s][op][tid];
        float n0 = fmaxf(fmaf(W[OFF_XS + 2 * op], __low2float(u), a0), 0.f);
        float n1 = fmaxf(fmaf(W[OFF_XS + 2 * op + 1], __high2float(u), a1), 0.f);
        Xh[s][op][tid] = __floats2half2_rn(n0, n1);
      }
    }

    // ---- k==0: cf + emb1 -> h ----
    if (k == 0) {
      float tv[48];
#pragma unroll
      for (int o = 0; o < 48; o++) tv[o] = W[OFF_BCF + o];
#pragma unroll 1
      for (int s = 0; s < 2; s++) {
#pragma unroll 1
        for (int cp = 0; cp < 24; cp++) {
          __half2 u = Xh[s][cp][tid];
          float x0c = __low2float(u), x1c = __high2float(u);
          const float* w0 = &W[OFF_CFT + (s * 48 + 2 * cp) * 48];
#pragma unroll
          for (int o = 0; o < 48; o++) tv[o] = fmaf(w0[o], x0c, tv[o]);
#pragma unroll
          for (int o = 0; o < 48; o++) tv[o] = fmaf(w0[48 + o], x1c, tv[o]);
        }
      }
#pragma unroll
      for (int o = 0; o < 48; o++) tv[o] = fmaxf(tv[o], 0.f);
      // h = gelu(WE1 tv + BE1)  (k0 only; fully unrolled, tv/h static)
#pragma unroll
      for (int o = 0; o < 24; o++) {
        float a = W[OFF_BE1 + o];
#pragma unroll
        for (int c = 0; c < 48; c++) a = fmaf(W[OFF_WE1 + o * 48 + c], tv[c], a);
        h[o] = gelu_f(a);
      }
    }

    // ---- scores: s(s,qh) = sum_c X_s[c]*(M[c].h + C[c]) + d.h + e ----
    float s1[4], s2[4];
    {
      float b1a = W[OFF_E4 + 0], b1b = W[OFF_E4 + 1], b2a = W[OFF_E4 + 2], b2b = W[OFF_E4 + 3];
#pragma unroll
      for (int j = 0; j < 24; j++) {
        b1a = fmaf(W[OFF_D1A + j], h[j], b1a);
        b1b = fmaf(W[OFF_D1B + j], h[j], b1b);
        b2a = fmaf(W[OFF_D2A + j], h[j], b2a);
        b2b = fmaf(W[OFF_D2B + j], h[j], b2b);
      }
      s1[0] = b1a; s1[2] = b1a; s1[1] = b1b; s1[3] = b1b;
      s2[0] = b2a; s2[2] = b2a; s2[1] = b2b; s2[3] = b2b;
    }
#pragma unroll 1
    for (int cp = 0; cp < 24; cp++) {
      __half2 u0 = Xh[0][cp][tid], u1 = Xh[1][cp][tid];
#pragma unroll
      for (int ch = 0; ch < 2; ch++) {
        int c = 2 * cp + ch;
        const float* m1a = &W[OFF_M1A + c * 24];
        const float* m1b = &W[OFF_M1B + c * 24];
        const float* m2a = &W[OFF_M2A + c * 24];
        const float* m2b = &W[OFF_M2B + c * 24];
        float z1a = W[OFF_C1A + c], z1b = W[OFF_C1B + c];
        float z2a = W[OFF_C2A + c], z2b = W[OFF_C2B + c];
#pragma unroll
        for (int j = 0; j < 24; j++) {
          z1a = fmaf(m1a[j], h[j], z1a);
          z1b = fmaf(m1b[j], h[j], z1b);
          z2a = fmaf(m2a[j], h[j], z2a);
          z2b = fmaf(m2b[j], h[j], z2b);
        }
        float x0 = ch ? __high2float(u0) : __low2float(u0);
        float x1 = ch ? __high2float(u1) : __low2float(u1);
        s1[0] = fmaf(x0, z1a, s1[0]); s1[1] = fmaf(x0, z1b, s1[1]);
        s1[2] = fmaf(x1, z1a, s1[2]); s1[3] = fmaf(x1, z1b, s1[3]);
        s2[0] = fmaf(x0, z2a, s2[0]); s2[1] = fmaf(x0, z2b, s2[1]);
        s2[2] = fmaf(x1, z2a, s2[2]); s2[3] = fmaf(x1, z2b, s2[3]);
      }
    }
    // softmax over 4
    {
      float m1 = fmaxf(fmaxf(s1[0], s1[1]), fmaxf(s1[2], s1[3]));
      float e0 = __expf(s1[0] - m1), e1 = __expf(s1[1] - m1), e2 = __expf(s1[2] - m1), e3 = __expf(s1[3] - m1);
      float inv = 1.f / (e0 + e1 + e2 + e3);
      s1[0] = e0 * inv; s1[1] = e1 * inv; s1[2] = e2 * inv; s1[3] = e3 * inv;
      float m2 = fmaxf(fmaxf(s2[0], s2[1]), fmaxf(s2[2], s2[3]));
      float f0 = __expf(s2[0] - m2), f1 = __expf(s2[1] - m2), f2 = __expf(s2[2] - m2), f3 = __expf(s2[3] - m2);
      float jnv = 1.f / (f0 + f1 + f2 + f3);
      s2[0] = f0 * jnv; s2[1] = f1 * jnv; s2[2] = f2 * jnv; s2[3] = f3 * jnv;
    }

    // ---- values fused with emb1: hp[o] = BE1 + bias-part + sum_c coef*P[c][o] ----
    float hp[24];
    {
      float q1l = s1[0] + s1[2], q1h = s1[1] + s1[3];
      float q2l = s2[0] + s2[2], q2h = s2[1] + s2[3];
#pragma unroll
      for (int o = 0; o < 24; o++) {
        float a = W[OFF_BE1 + o];
        a = fmaf(q1l, W[OFF_Q1L + o], a);
        a = fmaf(q1h, W[OFF_Q1H + o], a);
        a = fmaf(q2l, W[OFF_Q2L + o], a);
        a = fmaf(q2h, W[OFF_Q2H + o], a);
        hp[o] = a;
      }
    }
#pragma unroll 1
    for (int cp = 0; cp < 24; cp++) {
      __half2 u0 = Xh[0][cp][tid], u1 = Xh[1][cp][tid];
#pragma unroll
      for (int ch = 0; ch < 2; ch++) {
        int c = 2 * cp + ch;
        float x0 = ch ? __high2float(u0) : __low2float(u0);
        float x1 = ch ? __high2float(u1) : __low2float(u1);
        float cA = fmaf(s1[0], x0, s1[2] * x1);
        float cB = fmaf(s1[1], x0, s1[3] * x1);
        float cC = fmaf(s2[0], x0, s2[2] * x1);
        float cD = fmaf(s2[1], x0, s2[3] * x1);
        const float* p1l = &W[OFF_P1L + c * 24];
        const float* p1h = &W[OFF_P1H + c * 24];
        const float* p2l = &W[OFF_P2L + c * 24];
        const float* p2h = &W[OFF_P2H + c * 24];
#pragma unroll
        for (int o = 0; o < 24; o++) {
          float a = hp[o];
          a = fmaf(cA, p1l[o], a);
          a = fmaf(cB, p1h[o], a);
          a = fmaf(cC, p2l[o], a);
          a = fmaf(cD, p2h[o], a);
          hp[o] = a;
        }
      }
    }
#pragma unroll
    for (int o = 0; o < 24; o++) h[o] = gelu_f(hp[o]);
  }

  // ---- final: out = WE2 h + BE2 ----
  float* po = out + (size_t)b * 48 * HWS + n;
#pragma unroll 1
  for (int op = 0; op < 24; op++) {
    const float* w0 = &W[OFF_WE2R + (2 * op) * 24];
    float a0 = W[OFF_BE2 + 2 * op], a1 = W[OFF_BE2 + 2 * op + 1];
#pragma unroll
    for (int j = 0; j < 24; j++) a0 = fmaf(w0[j], h[j], a0);
#pragma unroll
    for (int j = 0; j < 24; j++) a1 = fmaf(w0[24 + j], h[j], a1);
    po[(size_t)(2 * op) * HWS] = a0;
    po[(size_t)(2 * op + 1) * HWS] = a1;
  }
}

extern "C" void kernel_launch(void* const* d_in, const int* in_sizes, int n_in,
                              void* d_out, int out_size, void* d_ws, size_t ws_size,
                              hipStream_t stream) {
  PtrPack P;
  for (int i = 0; i < 48; i++) P.p[i] = (const float*)d_in[i];
  float* W = (float*)d_ws;

  fold_kernel<<<(WS_TOTAL + 255) / 256, 256, 0, stream>>>(P, W);
  fused_main<<<NPIX / T, T, 0, stream>>>(P.p[0], P.p[1], W, (float*)d_out);
}